// Round 8
// baseline (273.963 us; speedup 1.0000x reference)
//
#include <hip/hip_runtime.h>
#include <cstdint>
#include <cstddef>

#define NEG_SLOPE 0.2f

typedef __bf16 bf16x8 __attribute__((ext_vector_type(8)));
typedef float  f32x4  __attribute__((ext_vector_type(4)));

__device__ inline unsigned int bf16pair(float a, float b) {
    unsigned int ua = __float_as_uint(a), ub = __float_as_uint(b);
    ua += 0x7fffu + ((ua >> 16) & 1u);
    ub += 0x7fffu + ((ub >> 16) & 1u);
    return (ua >> 16) | (ub & 0xffff0000u);
}
__device__ inline unsigned short bf16r(float x) {
    unsigned int u = __float_as_uint(x);
    u += 0x7fffu + ((u >> 16) & 1u);
    return (unsigned short)(u >> 16);
}

// ---------------------------------------------------------------------------
// One-time W transpose+cast: Wt[n][k] = bf16(W[k][n]), for W1 and W2.
// ---------------------------------------------------------------------------
__global__ __launch_bounds__(256) void wtrans_kernel(
    const float* __restrict__ W1, const float* __restrict__ W2,
    unsigned short* __restrict__ Wt1, unsigned short* __restrict__ Wt2)
{
    __shared__ float tile[64][65];
    const float* W = (blockIdx.x < 4) ? W1 : W2;
    unsigned short* Wt = (blockIdx.x < 4) ? Wt1 : Wt2;
    const int tb = blockIdx.x & 3;
    const int k0 = (tb >> 1) * 64, n0 = (tb & 1) * 64;
    const int c = threadIdx.x & 63, r4 = threadIdx.x >> 6;
#pragma unroll
    for (int i = 0; i < 16; ++i) {
        const int r = i * 4 + r4;
        tile[r][c] = W[(size_t)(k0 + r) * 128 + n0 + c];
    }
    __syncthreads();
#pragma unroll
    for (int i = 0; i < 16; ++i) {
        const int nn = i * 4 + r4;
        Wt[(size_t)(n0 + nn) * 128 + k0 + c] = bf16r(tile[c][nn]);
    }
}

// ---------------------------------------------------------------------------
// MFMA GEMM (+optional fused CSR rank pass): feat16 = bf16(X @ W), el/er.
// Blocks [0, gemm_blocks) do a 64x128 GEMM tile (4 waves, K=128 in LDS).
// With RANK=true, blocks [gemm_blocks, ...) run the latency-bound CSR rank
// pass (rank[e] = atomicAdd(deg[dst[e]])) -- co-scheduled with the
// compute-bound GEMM blocks so its memory latency hides under MFMA work.
// Frag layouts (m89/m120-verified): A[m=lane&15][k=(lane>>4)*8+j];
// C/D col=lane&15, row=(lane>>4)*4+reg.
// ---------------------------------------------------------------------------
template <bool RANK>
__global__ __launch_bounds__(256, 3) void gemm_attn_kernel(
    const float* __restrict__ X, const unsigned short* __restrict__ Wt,
    const float* __restrict__ al, const float* __restrict__ ar,
    unsigned short* __restrict__ feat16, float* __restrict__ el,
    float* __restrict__ er, int n, int gemm_blocks,
    const int* __restrict__ dst, int* __restrict__ deg,
    int* __restrict__ rank, int E)
{
    __shared__ unsigned short sX[64][136];   // 17.0 KB (reused for store repack)
    __shared__ unsigned short sW[128][136];  // 34.0 KB

    const int t = threadIdx.x;

    if (RANK && (int)blockIdx.x >= gemm_blocks) {
        const int bid = blockIdx.x - gemm_blocks;
        const int e4 = (bid * 256 + t) * 4;
        if (e4 + 4 <= E) {
            const int4 d = *(const int4*)&dst[e4];
            int4 r;
            r.x = atomicAdd(&deg[d.x], 1);
            r.y = atomicAdd(&deg[d.y], 1);
            r.z = atomicAdd(&deg[d.z], 1);
            r.w = atomicAdd(&deg[d.w], 1);
            *(int4*)&rank[e4] = r;
        } else {
            for (int e = e4; e < E; ++e) rank[e] = atomicAdd(&deg[dst[e]], 1);
        }
        return;
    }

    const int rowbase = blockIdx.x * 64;

#pragma unroll
    for (int i = 0; i < 8; ++i) {
        const int idx = t + 256 * i;
        const int row = idx >> 5;
        const int kq  = (idx & 31) * 4;
        int g = rowbase + row; if (g >= n) g = n - 1;
        const float4 v = *(const float4*)&X[(size_t)g * 128 + kq];
        uint2 pk;
        pk.x = bf16pair(v.x, v.y);
        pk.y = bf16pair(v.z, v.w);
        *(uint2*)&sX[row][kq] = pk;
    }
#pragma unroll
    for (int i = 0; i < 8; ++i) {
        const int idx = t + 256 * i;
        const int row = idx >> 4;
        const int q   = idx & 15;
        *(uint4*)&sW[row][q * 8] = *(const uint4*)&Wt[(size_t)row * 128 + q * 8];
    }
    __syncthreads();

    const int lane = t & 63;
    const int w    = t >> 6;
    const int m    = lane & 15;
    const int g4   = lane >> 4;

    bf16x8 a[4];
#pragma unroll
    for (int ks = 0; ks < 4; ++ks)
        a[ks] = *(const bf16x8*)&sX[w * 16 + m][ks * 32 + g4 * 8];

    float elacc[4][4] = {{0}}, eracc[4][4] = {{0}};
    unsigned short fout[8][4];           // [ct-tile 0..7][r]

#pragma unroll
    for (int ct = 0; ct < 8; ct += 2) {
        f32x4 acc0 = {0.f, 0.f, 0.f, 0.f}, acc1 = {0.f, 0.f, 0.f, 0.f};
        const int n0 = ct * 16 + m, n1 = n0 + 16;
#pragma unroll
        for (int ks = 0; ks < 4; ++ks) {
            const bf16x8 b0 = *(const bf16x8*)&sW[n0][ks * 32 + g4 * 8];
            const bf16x8 b1 = *(const bf16x8*)&sW[n1][ks * 32 + g4 * 8];
            acc0 = __builtin_amdgcn_mfma_f32_16x16x32_bf16(a[ks], b0, acc0, 0, 0, 0);
            acc1 = __builtin_amdgcn_mfma_f32_16x16x32_bf16(a[ks], b1, acc1, 0, 0, 0);
        }
        const int h = ct >> 1;
        const float al0 = al[n0], ar0 = ar[n0];
        const float al1 = al[n1], ar1 = ar[n1];
#pragma unroll
        for (int r = 0; r < 4; ++r) {
            elacc[r][h] += acc0[r] * al0 + acc1[r] * al1;
            eracc[r][h] += acc0[r] * ar0 + acc1[r] * ar1;
            fout[ct][r]     = bf16r(acc0[r]);
            fout[ct + 1][r] = bf16r(acc1[r]);
        }
    }

    // ---- feat16 store via LDS repack (sX reused) ----
    __syncthreads();
#pragma unroll
    for (int ct = 0; ct < 8; ++ct)
#pragma unroll
        for (int r = 0; r < 4; ++r)
            sX[w * 16 + g4 * 4 + r][ct * 16 + m] = fout[ct][r];
    __syncthreads();
    {
        const int row = t >> 2;          // 0..63
        const int q   = t & 3;
        const int g   = rowbase + row;
        if (g < n) {
#pragma unroll
            for (int i = 0; i < 4; ++i) {
                const int c0 = q * 8 + i * 32;
                *(uint4*)&feat16[(size_t)g * 128 + c0] = *(const uint4*)&sX[row][c0];
            }
        }
    }

    // ---- el/er reduction over the 16 m-lanes ----
#pragma unroll
    for (int r = 0; r < 4; ++r)
#pragma unroll
        for (int h = 0; h < 4; ++h) {
            float a_ = elacc[r][h], b_ = eracc[r][h];
            a_ += __shfl_xor(a_, 1); b_ += __shfl_xor(b_, 1);
            a_ += __shfl_xor(a_, 2); b_ += __shfl_xor(b_, 2);
            a_ += __shfl_xor(a_, 4); b_ += __shfl_xor(b_, 4);
            a_ += __shfl_xor(a_, 8); b_ += __shfl_xor(b_, 8);
            elacc[r][h] = a_; eracc[r][h] = b_;
        }
    if (m == 0) {
#pragma unroll
        for (int r = 0; r < 4; ++r) {
            const int row = rowbase + w * 16 + g4 * 4 + r;
            if (row < n) {
#pragma unroll
                for (int h = 0; h < 4; ++h) {
                    el[(size_t)row * 4 + h] = elacc[r][h];
                    er[(size_t)row * 4 + h] = eracc[r][h];
                }
            }
        }
    }
}

// ---------------------------------------------------------------------------
// NOTE: assumes n % 4 == 0 (n = 50000 here).
__global__ __launch_bounds__(1024) void scan_kernel(
    const int* __restrict__ deg, int* __restrict__ off, int n)
{
    __shared__ int wsums[16];
    __shared__ int s_carry;
    const int tid  = threadIdx.x;
    const int lane = tid & 63;
    const int wid  = tid >> 6;

    if (tid == 0) { s_carry = 0; off[0] = 0; }
    __syncthreads();

    const int n4 = n >> 2;
    const int4* __restrict__ deg4 = (const int4*)deg;

    for (int base = 0; base < n4; base += 1024) {
        const int i4 = base + tid;
        int4 v = make_int4(0, 0, 0, 0);
        if (i4 < n4) v = deg4[i4];
        const int t0 = v.x, t1 = t0 + v.y, t2 = t1 + v.z, t3 = t2 + v.w;

        int x = t3;
#pragma unroll
        for (int d = 1; d < 64; d <<= 1) {
            int y = __shfl_up(x, d);
            if (lane >= d) x += y;
        }
        if (lane == 63) wsums[wid] = x;
        __syncthreads();

        if (wid == 0 && lane < 16) {
            int xx = wsums[lane];
#pragma unroll
            for (int d = 1; d < 16; d <<= 1) {
                int y = __shfl_up(xx, d);
                if (lane >= d) xx += y;
            }
            wsums[lane] = xx;
        }
        __syncthreads();

        const int wp   = (wid == 0) ? 0 : wsums[wid - 1];
        const int excl = s_carry + wp + (x - t3);
        if (i4 < n4) {
            off[4 * i4 + 1] = excl + t0;
            off[4 * i4 + 2] = excl + t1;
            off[4 * i4 + 3] = excl + t2;
            off[4 * i4 + 4] = excl + t3;
        }
        __syncthreads();
        if (tid == 0) s_carry += wsums[15];
        __syncthreads();
    }
}

__global__ void place_kernel(const int* __restrict__ src, const int* __restrict__ dst,
                             const int* __restrict__ off, const int* __restrict__ rank,
                             int* __restrict__ csr_src, int E)
{
    const int e4 = (blockIdx.x * blockDim.x + threadIdx.x) * 4;
    if (e4 + 4 <= E) {
        const int4 s = *(const int4*)&src[e4];
        const int4 d = *(const int4*)&dst[e4];
        const int4 r = *(const int4*)&rank[e4];
        const int o0 = off[d.x], o1 = off[d.y], o2 = off[d.z], o3 = off[d.w];
        csr_src[o0 + r.x] = s.x;
        csr_src[o1 + r.y] = s.y;
        csr_src[o2 + r.z] = s.z;
        csr_src[o3 + r.w] = s.w;
    } else {
        for (int e = e4; e < E; ++e)
            csr_src[off[dst[e]] + rank[e]] = src[e];
    }
}

// ---------------------------------------------------------------------------
// Aggregation: one wave per destination node, 16-deep load batching (all 16
// csr idx loads, then 16 el loads, then 16 feat loads before any math) to
// maximize outstanding loads per wave. leaky_relu(x) = max(x, 0.2x).
// Lane owns dim pair (2l, 2l+1) of head l>>4 -> per-edge feat16 read is one
// coalesced 256B wave-load.
// ---------------------------------------------------------------------------
template <bool LAYER2>
__global__ __launch_bounds__(256, 4) void agg_kernel(
    const int* __restrict__ off, const int* __restrict__ csr_src,
    const unsigned short* __restrict__ feat16, const float* __restrict__ el,
    const float* __restrict__ er, const float* __restrict__ resid,
    const float* __restrict__ bias, float* __restrict__ out, int n)
{
    const int lane = threadIdx.x & 63;
    const int node = blockIdx.x * 4 + (threadIdx.x >> 6);
    if (node >= n) return;

    const int h  = lane >> 4;
    const int d0 = 2 * lane;

    const float erh = er[(size_t)node * 4 + h];
    const unsigned int* __restrict__ fb = (const unsigned int*)feat16;

    const int beg = off[node], end = off[node + 1];

    float acc0 = 0.f, acc1 = 0.f, sw = 0.f;
    int j = beg;

    for (; j + 16 <= end; j += 16) {
        int s[16]; float ev[16]; unsigned int uv[16];
#pragma unroll
        for (int q = 0; q < 16; ++q) s[q] = csr_src[j + q];
#pragma unroll
        for (int q = 0; q < 16; ++q) ev[q] = el[(size_t)s[q] * 4 + h];
#pragma unroll
        for (int q = 0; q < 16; ++q) uv[q] = fb[(size_t)s[q] * 64 + lane];
#pragma unroll
        for (int q = 0; q < 16; ++q) {
            float a = ev[q] + erh;
            a = fmaxf(a, NEG_SLOPE * a);
            const float wq = __expf(a);
            acc0 += wq * __uint_as_float(uv[q] << 16);
            acc1 += wq * __uint_as_float(uv[q] & 0xffff0000u);
            sw += wq;
        }
    }
    for (; j + 4 <= end; j += 4) {
        int s[4]; float ev[4]; unsigned int uv[4];
#pragma unroll
        for (int q = 0; q < 4; ++q) s[q] = csr_src[j + q];
#pragma unroll
        for (int q = 0; q < 4; ++q) ev[q] = el[(size_t)s[q] * 4 + h];
#pragma unroll
        for (int q = 0; q < 4; ++q) uv[q] = fb[(size_t)s[q] * 64 + lane];
#pragma unroll
        for (int q = 0; q < 4; ++q) {
            float a = ev[q] + erh;
            a = fmaxf(a, NEG_SLOPE * a);
            const float wq = __expf(a);
            acc0 += wq * __uint_as_float(uv[q] << 16);
            acc1 += wq * __uint_as_float(uv[q] & 0xffff0000u);
            sw += wq;
        }
    }
    for (; j < end; ++j) {
        const int s = csr_src[j];
        float a = el[(size_t)s * 4 + h] + erh;
        a = fmaxf(a, NEG_SLOPE * a);
        const float wq = __expf(a);
        const unsigned int u = fb[(size_t)s * 64 + lane];
        acc0 += wq * __uint_as_float(u << 16);
        acc1 += wq * __uint_as_float(u & 0xffff0000u);
        sw += wq;
    }

    const float inv = 1.f / fmaxf(sw, 1e-9f);
    const float2 rs = *(const float2*)&resid[(size_t)node * 128 + d0];
    float v0 = acc0 * inv + rs.x + bias[d0];
    float v1 = acc1 * inv + rs.y + bias[d0 + 1];

    if (!LAYER2) {
        v0 = (v0 > 0.f) ? v0 : expm1f(v0);
        v1 = (v1 > 0.f) ? v1 : expm1f(v1);
        *(float2*)&out[(size_t)node * 128 + d0] = make_float2(v0, v1);
    } else {
        float s0 = v0, s1 = v1;
        s0 += __shfl_xor(s0, 16); s1 += __shfl_xor(s1, 16);
        s0 += __shfl_xor(s0, 32); s1 += __shfl_xor(s1, 32);
        if (lane < 16)
            *(float2*)&out[(size_t)node * 32 + 2 * lane] =
                make_float2(s0 * 0.25f, s1 * 0.25f);
    }
}

// ---------------------------------------------------------------------------
extern "C" void kernel_launch(void* const* d_in, const int* in_sizes, int n_in,
                              void* d_out, int out_size, void* d_ws, size_t ws_size,
                              hipStream_t stream)
{
    const float* x   = (const float*)d_in[0];
    const float* W1  = (const float*)d_in[1];
    const float* al1 = (const float*)d_in[2];
    const float* ar1 = (const float*)d_in[3];
    const float* b1  = (const float*)d_in[4];
    const float* W2  = (const float*)d_in[5];
    const float* al2 = (const float*)d_in[6];
    const float* ar2 = (const float*)d_in[7];
    const float* b2  = (const float*)d_in[8];
    const int*   src = (const int*)d_in[9];
    const int*   dst = (const int*)d_in[10];

    const int n = in_sizes[0] / 128;
    const int E = in_sizes[9];
    float* out = (float*)d_out;

    char* p = (char*)d_ws;
    float* h1    = (float*)p;          p += (size_t)n * 128 * sizeof(float);
    unsigned short* feat16 = (unsigned short*)p; p += (size_t)n * 128 * sizeof(unsigned short);
    float* el    = (float*)p;          p += (size_t)n * 4 * sizeof(float);
    float* er    = (float*)p;          p += (size_t)n * 4 * sizeof(float);
    int* off     = (int*)p;            p += (size_t)(n + 1) * sizeof(int);
    int* deg     = (int*)p;            p += (size_t)n * sizeof(int);
    int* rank    = (int*)p;            p += (size_t)E * sizeof(int);
    int* csr     = (int*)p;            p += (size_t)E * sizeof(int);
    unsigned short* wt1 = (unsigned short*)p; p += (size_t)128 * 128 * sizeof(unsigned short);
    unsigned short* wt2 = (unsigned short*)p; p += (size_t)128 * 128 * sizeof(unsigned short);

    hipMemsetAsync(deg, 0, (size_t)n * sizeof(int), stream);

    const int gemm_grid  = (n + 63) / 64;
    const int edge4_grid = (E / 4 + 255) / 256;
    const int agg_grid   = (n + 3) / 4;

    wtrans_kernel<<<8, 256, 0, stream>>>(W1, W2, wt1, wt2);
    // gemm1 with fused CSR rank pass (extra blocks)
    gemm_attn_kernel<true><<<gemm_grid + edge4_grid, 256, 0, stream>>>(
        x, wt1, al1, ar1, feat16, el, er, n, gemm_grid, dst, deg, rank, E);
    scan_kernel<<<1, 1024, 0, stream>>>(deg, off, n);
    place_kernel<<<edge4_grid, 256, 0, stream>>>(src, dst, off, rank, csr, E);
    agg_kernel<false><<<agg_grid, 256, 0, stream>>>(off, csr, feat16, el, er, x, b1, h1, n);
    gemm_attn_kernel<false><<<gemm_grid, 256, 0, stream>>>(
        h1, wt2, al2, ar2, feat16, el, er, n, gemm_grid, nullptr, nullptr, nullptr, 0);
    agg_kernel<true><<<agg_grid, 256, 0, stream>>>(off, csr, feat16, el, er, h1, b2, out, n);
}